// Round 10
// baseline (88.812 us; speedup 1.0000x reference)
//
#include <hip/hip_runtime.h>
#include <math.h>

// Problem shape (fixed by the reference): B=4, S=4, N=2048, D=2048
#define NB 4
#define NS 4
#define NN 2048
#define ND 2048
#define NTHREADS 512
#define KPB 2            // (b,n) pairs per block, software-pipelined
#define SQRT_D 45.254833995939045f   // sqrt(2048)

typedef float f32x4 __attribute__((ext_vector_type(4)));

// Compaction-butterfly ship, literal indices only (R3 lesson, R5/R7/R9-proven).
#define SHIP(I, H, M_) {                                      \
    const float keep_ = hi_ ? v[(I)+(H)] : v[(I)];            \
    const float give_ = hi_ ? v[(I)] : v[(I)+(H)];            \
    v[(I)] = keep_ + __shfl_xor(give_, (M_)); }

#define BUTTERFLY()                                                          \
    { const bool hi_ = (lane & 1) != 0;                                      \
      SHIP(0,16,1)  SHIP(1,16,1)  SHIP(2,16,1)  SHIP(3,16,1)                 \
      SHIP(4,16,1)  SHIP(5,16,1)  SHIP(6,16,1)  SHIP(7,16,1)                 \
      SHIP(8,16,1)  SHIP(9,16,1)  SHIP(10,16,1) SHIP(11,16,1)                \
      SHIP(12,16,1) SHIP(13,16,1) SHIP(14,16,1) SHIP(15,16,1) }              \
    { const bool hi_ = (lane & 2) != 0;                                      \
      SHIP(0,8,2) SHIP(1,8,2) SHIP(2,8,2) SHIP(3,8,2)                        \
      SHIP(4,8,2) SHIP(5,8,2) SHIP(6,8,2) SHIP(7,8,2) }                      \
    { const bool hi_ = (lane & 4) != 0;                                      \
      SHIP(0,4,4) SHIP(1,4,4) SHIP(2,4,4) SHIP(3,4,4) }                      \
    { const bool hi_ = (lane & 8) != 0;                                      \
      SHIP(0,2,8) SHIP(1,2,8) }                                              \
    { const bool hi_ = (lane & 16) != 0;                                     \
      SHIP(0,1,16) }

// One (b,n) iteration. XC0..3 = current x (f32x4 named regs), XN0..3 = next
// x destination. K, PREF are literals at every expansion (R3/R9 discipline).
#define ITER(XC0, XC1, XC2, XC3, XN0, XN1, XN2, XN3, K, PREF)                \
  {                                                                          \
    float v[32];                                                             \
    _Pragma("unroll") for (int q = 0; q < 32; ++q) v[q] = 0.f;               \
    {                                                                        \
      f32x4 g4 = *(const f32x4*)(gamma + d);                                 \
      _Pragma("unroll") for (int e = 0; e < 4; ++e) {                        \
        v[0]  = __builtin_fmaf(XC0[e], XC0[e], v[0]);                        \
        v[7]  = __builtin_fmaf(XC1[e], XC1[e], v[7]);                        \
        v[14] = __builtin_fmaf(XC2[e], XC2[e], v[14]);                       \
        v[21] = __builtin_fmaf(XC3[e], XC3[e], v[21]);                       \
      }                                                                      \
      _Pragma("unroll") for (int j = 0; j < 6; ++j) {                        \
        const float* wsrc = (j < 5) ? (w_alpha + (size_t)j * ND + d)         \
                                    : (w_beta + d);                          \
        f32x4 w4 = *(const f32x4*)wsrc;                                      \
        f32x4 wg = w4 + w4 * g4;        /* w * (1 + gamma) */                \
        _Pragma("unroll") for (int e = 0; e < 4; ++e) {                      \
          v[1 + j]  = __builtin_fmaf(XC0[e], wg[e], v[1 + j]);               \
          v[8 + j]  = __builtin_fmaf(XC1[e], wg[e], v[8 + j]);               \
          v[15 + j] = __builtin_fmaf(XC2[e], wg[e], v[15 + j]);              \
          v[22 + j] = __builtin_fmaf(XC3[e], wg[e], v[22 + j]);              \
        }                                                                    \
      }                                                                      \
    }                                                                        \
    /* prefetch next bn's x: lands during butterfly+barriers+tanh+apply */   \
    if (PREF) {                                                              \
      const float* np_ = xp + ((K) + 1) * ND;                                \
      XN0 = *(const f32x4*)(np_);                                            \
      XN1 = *(const f32x4*)(np_ + row_stride);                               \
      XN2 = *(const f32x4*)(np_ + 2 * row_stride);                           \
      XN3 = *(const f32x4*)(np_ + 3 * row_stride);                           \
    }                                                                        \
    BUTTERFLY()                                                              \
    const float tot##K = v[0] + __shfl_xor(v[0], 32);                        \
    if (lane < 32) red[wave][bidx] = tot##K;                                 \
    __syncthreads();                                                         \
    if (tid < 24) {                                                          \
      const int s_ = tid / 6;                                                \
      const int j_ = tid % 6;                                                \
      float ssq_ = 0.f, dot_ = 0.f;                                          \
      _Pragma("unroll") for (int w = 0; w < 8; ++w) {                        \
        ssq_ += red[w][s_ * 7];                                              \
        dot_ += red[w][s_ * 7 + 1 + j_];                                     \
      }                                                                      \
      const float rs_ = SQRT_D / fmaxf(sqrtf(ssq_), 1e-12f);                 \
      const float th_ = tanhf(dot_ * rs_);                                   \
      asb[s_][j_] = (j_ < 5) ? (th_ * sa + static_alpha[s_ * 5 + j_])        \
                             : (th_ * sb + static_beta[s_]);                 \
    }                                                                        \
    __syncthreads();                                                         \
    {                                                                        \
      float M[NS][NS];                                                       \
      _Pragma("unroll") for (int so = 0; so < NS; ++so)                      \
        _Pragma("unroll") for (int si = 0; si < NS; ++si)                    \
          M[so][si] = __builtin_fmaf(asb[so][5], asb[si][0],                 \
                                     asb[si][so + 1]);                       \
      float* op_ = op + (K) * ND;                                            \
      _Pragma("unroll") for (int so = 0; so < NS; ++so) {                    \
        f32x4 o;                                                             \
        _Pragma("unroll") for (int e = 0; e < 4; ++e)                        \
          o[e] = M[so][0] * XC0[e] + M[so][1] * XC1[e]                       \
               + M[so][2] * XC2[e] + M[so][3] * XC3[e];                      \
        __builtin_nontemporal_store(o, (f32x4*)(op_ + (size_t)so * row_stride)); \
      }                                                                      \
    }                                                                        \
  }

// 512 threads, one f32x4 chunk per thread, 2 bn per block with prefetch.
// Budget (R4/R8 lesson: demand>cap => array demotion): v[32]+xc[16]+xn[16]
// + temps ~= 100 peak < 128 cap at (512,4). 16 waves/CU.
__global__ __launch_bounds__(NTHREADS, 4)
void hyperconn_kernel(const float* __restrict__ residuals,
                      const float* __restrict__ gamma,
                      const float* __restrict__ w_alpha,
                      const float* __restrict__ scale_alpha,
                      const float* __restrict__ static_alpha,
                      const float* __restrict__ w_beta,
                      const float* __restrict__ scale_beta,
                      const float* __restrict__ static_beta,
                      float* __restrict__ out)
{
    __shared__ float red[8][32];   // per-wave compacted sums (idx = brev5)
    __shared__ float asb[NS][6];   // [s][0..4]=alpha row, [s][5]=beta

    const int tid  = threadIdx.x;
    const int blk  = blockIdx.x;              // 0 .. 4095
    const int b    = blk >> 10;               // 1024 blocks per b
    const int n0   = (blk & 1023) * KPB;      // adjacent n pair
    const int wave = tid >> 6;
    const int lane = tid & 63;
    const int d    = tid << 2;                // one f32x4 chunk per thread

    const size_t row_stride = (size_t)NN * ND;
    const float* xp = residuals + (size_t)(b * NS) * row_stride + (size_t)n0 * ND + d;
    float*       op = out       + (size_t)(b * NS) * row_stride + (size_t)n0 * ND + d;

    const float sa = scale_alpha[0], sb = scale_beta[0];
    const int bidx = ((lane & 1) << 4) | ((lane & 2) << 2) | (lane & 4)
                   | ((lane & 8) >> 2) | ((lane & 16) >> 4);   // brev5(lane&31)

    // Prologue: load bn0's x
    f32x4 a0 = *(const f32x4*)(xp);
    f32x4 a1 = *(const f32x4*)(xp + row_stride);
    f32x4 a2 = *(const f32x4*)(xp + 2 * row_stride);
    f32x4 a3 = *(const f32x4*)(xp + 3 * row_stride);
    f32x4 c0, c1, c2, c3;   // bn1's x, filled by iteration 0's prefetch

    ITER(a0, a1, a2, a3, c0, c1, c2, c3, 0, 1)
    ITER(c0, c1, c2, c3, a0, a1, a2, a3, 1, 0)
}

extern "C" void kernel_launch(void* const* d_in, const int* in_sizes, int n_in,
                              void* d_out, int out_size, void* d_ws, size_t ws_size,
                              hipStream_t stream) {
    const float* residuals    = (const float*)d_in[0];
    const float* gamma        = (const float*)d_in[1];
    const float* w_alpha      = (const float*)d_in[2];
    const float* scale_alpha  = (const float*)d_in[3];
    const float* static_alpha = (const float*)d_in[4];
    const float* w_beta       = (const float*)d_in[5];
    const float* scale_beta   = (const float*)d_in[6];
    const float* static_beta  = (const float*)d_in[7];
    float* out = (float*)d_out;

    const int grid = NB * NN / KPB;  // 4096 blocks, 2 bn each
    hyperconn_kernel<<<grid, NTHREADS, 0, stream>>>(
        residuals, gamma, w_alpha, scale_alpha, static_alpha,
        w_beta, scale_beta, static_beta, out);
}